// Round 6
// baseline (338.034 us; speedup 1.0000x reference)
//
#include <hip/hip_runtime.h>
#include <math.h>

namespace {
constexpr int B = 512, S = 64, K = 8, D = 16, NR = 64, NSTEPS = 100, NUNITS = 128;
constexpr int NROWS = 73;   // 64 q2 rows + 8 q1 rows + 1 q0 row per pair
}

// Intra-wave LDS fence (same-wave DS visibility; no vmcnt drain, no
// cross-wave coupling). Proven correct in R5.
#define WAVE_LDS_FENCE() __asm__ volatile("s_waitcnt lgkmcnt(0)" ::: "memory")

// Row r stored at float-offset 16r + 4*((r>>3)&7): 16B-aligned (float4-able),
// and the k-dependent 4-float stagger breaks the "8k*stride = 0 mod 32 banks"
// aliasing so per-k reads spread across banks (<=2-4 way).
__device__ __forceinline__ int rowoff(int r) { return r * 16 + ((r >> 3) & 7) * 4; }

// ---------------------------------------------------------------------------
// Fused prep: (t<64) w_tab[b][r] user-relation scores; (64<=t<128) hop-1
// index prefetch e1s/r0s; (b==0, t in [128,228)) diffusion alpha schedule.
// ---------------------------------------------------------------------------
__global__ __launch_bounds__(256) void k_prep_all(
    const float* __restrict__ usr_emb, const float* __restrict__ rel_emb,
    const int* __restrict__ u, const int* __restrict__ click_seq,
    const int* __restrict__ adj_ent, const int* __restrict__ adj_rel,
    float* __restrict__ w_tab, int* __restrict__ e1s, int* __restrict__ r0s,
    float* __restrict__ sa, float* __restrict__ so)
{
    int b = blockIdx.x, t = threadIdx.x;
    if (t < 64) {
        const float* ur = usr_emb + (long)u[b] * D;
        const float* rr = rel_emb + t * D;
        float s = 0.f;
#pragma unroll
        for (int d = 0; d < D; ++d) s += ur[d] * rr[d];
        w_tab[b * NR + t] = s * (1.0f / 16.0f);
    } else if (t < 128) {
        int p = b * S + (t - 64);
        int e0 = click_seq[p];
        const int4* ae = (const int4*)(adj_ent + (long)e0 * K);
        const int4* ar = (const int4*)(adj_rel + (long)e0 * K);
        int4 a0 = ae[0], a1 = ae[1], b0 = ar[0], b1 = ar[1];
        int4* oe = (int4*)(e1s + (long)p * K);
        int4* orr = (int4*)(r0s + (long)p * K);
        oe[0] = a0; oe[1] = a1;
        orr[0] = b0; orr[1] = b1;
    } else if (b == 0 && (t - 128) < NSTEPS) {
        int i = t - 128;
        float prod = 1.0f;
        for (int jj = 0; jj <= i; ++jj) {
            float x = -6.0f + (float)jj * (12.0f / 99.0f);
            float sig = 1.0f / (1.0f + expf(-x));
            prod *= (1.0f - (sig * (0.005f - 1e-5f) + 1e-5f));
        }
        sa[i] = sqrtf(prod);
        so[i] = sqrtf(1.0f - prod);
    }
}

// ---------------------------------------------------------------------------
// KGCN R6: cooperative line-merged gather. 4 wave-private pairs per block,
// zero block barriers. All 73 ent_emb rows of a pair are staged into LDS by
// lane->(row=t/4, seg=t%4): 4 consecutive lanes cover one 64-B row -> the
// per-inst coalescer merges them into one line request (R5: one lane owned a
// whole row -> 4 insts x 64 distinct lines each = 4x the address traffic).
// Cross-lane state (rel-score table, p1, p0, ag0, M1, h1) lives in registers
// and moves by __shfl; only rowbuf/Ws/Ms/idxs remain in LDS.
// ---------------------------------------------------------------------------
__global__ __launch_bounds__(256) void k_kgcn(
    const float* __restrict__ ent_emb,
    const float* __restrict__ w_tab,      // [B, NR]
    const int* __restrict__ click_seq,    // [B*S]
    const int* __restrict__ adj_ent,      // [NE, K]
    const int* __restrict__ adj_rel,      // [NE, K]
    const int* __restrict__ e1s,          // [B*S*K] precomputed
    const int* __restrict__ r0s,          // [B*S*K] precomputed
    const float* __restrict__ agg_W,      // [D, D]
    const float* __restrict__ agg_b,      // [D]
    float* __restrict__ item)             // [B*S, D]
{
    __shared__ int   idxs[4][80];         // 73 used: 0..63 q2(k,j), 64..71 q1(k), 72 q0
    __shared__ float rowbuf[4][1184];     // swizzled rows, see rowoff()
    __shared__ float Ws[4][D][17];        // agg_W, row-major, +1 pad
    __shared__ float Ms[4][K][18];        // hop-1 aggregate (even stride for b64)

    const int tid = threadIdx.x;
    const int w = tid >> 6;               // wave in block (pair slot)
    const int lane = tid & 63;
    const int p = blockIdx.x * 4 + w;     // pair id = b*S + s
    const int b = p >> 6;
    const int k = lane >> 3, j = lane & 7;

    // ---- index + small staging loads (all issued up front)
    const int e0   = click_seq[p];
    const int e1k  = e1s[(long)p * K + k];
    const int r0k  = r0s[(long)p * K + k];
    const int e2kj = adj_ent[(long)e1k * K + j];
    const int r1kj = adj_rel[(long)e1k * K + j];
    const float wv   = w_tab[b * NR + lane];   // lane L holds relation L's score
    const float bval = agg_b[lane & 15];       // bias for this lane's output col
    {
        const float4 wq = ((const float4*)agg_W)[lane];   // agg_W[4L..4L+3]
        int row = lane >> 2, col = (lane & 3) * 4;
        Ws[w][row][col] = wq.x; Ws[w][row][col + 1] = wq.y;
        Ws[w][row][col + 2] = wq.z; Ws[w][row][col + 3] = wq.w;
    }
    idxs[w][lane] = e2kj;
    if (j == 0) idxs[w][64 + k] = e1k;
    if (lane == 0) idxs[w][72] = e0;
    WAVE_LDS_FENCE();   // idxs (and Ws) visible to this wave

    // ---- softmaxes, register-only (wv gather via dynamic shfl)
    float s1 = __shfl(wv, r1kj);
    float m1 = s1;
    m1 = fmaxf(m1, __shfl_xor(m1, 1));
    m1 = fmaxf(m1, __shfl_xor(m1, 2));
    m1 = fmaxf(m1, __shfl_xor(m1, 4));
    float ex = expf(s1 - m1);
    float den = ex;
    den += __shfl_xor(den, 1); den += __shfl_xor(den, 2); den += __shfl_xor(den, 4);
    const float p1 = ex / den;

    float s0 = __shfl(wv, r0k);
    float m0 = s0;
    m0 = fmaxf(m0, __shfl_xor(m0, 8));
    m0 = fmaxf(m0, __shfl_xor(m0, 16));
    m0 = fmaxf(m0, __shfl_xor(m0, 32));
    float e0x = expf(s0 - m0);
    float d0 = e0x;
    d0 += __shfl_xor(d0, 8); d0 += __shfl_xor(d0, 16); d0 += __shfl_xor(d0, 32);
    const float p0 = e0x / d0;

    // ---- cooperative row gather: task t -> (row t>>2, seg t&3); 4 adjacent
    // lanes cover one 64-B row = one merged line request per row per inst.
#pragma unroll
    for (int it = 0; it < 5; ++it) {
        int t = it * 64 + lane;
        if (t < NROWS * 4) {
            int r = t >> 2, seg = t & 3;
            const float4 v = *(const float4*)(ent_emb + (long)idxs[w][r] * D + seg * 4);
            *(float4*)&rowbuf[w][rowoff(r) + seg * 4] = v;
        }
    }
    WAVE_LDS_FENCE();   // rowbuf ready

    // ---- hop-1 aggregation: lane=(k,h) owns dims 2h,2h+1 of M[k]
    const int h = j;    // same bits, renamed for clarity
    float acc0 = 0.f, acc1 = 0.f;
#pragma unroll
    for (int jp = 0; jp < 8; ++jp) {
        float pw = __shfl(p1, k * 8 + jp);
        const float2 q = *(const float2*)&rowbuf[w][rowoff(k * 8 + jp) + 2 * h];
        acc0 += pw * q.x;
        acc1 += pw * q.y;
    }
    {
        const float2 q1v = *(const float2*)&rowbuf[w][rowoff(64 + k) + 2 * h];
        Ms[w][k][2 * h]     = q1v.x + acc0;   // self + neigh_agg
        Ms[w][k][2 * h + 1] = q1v.y + acc1;
    }

    // ---- ag0[d] = sum_k p0_k * q1[k][d]; lane=(kq=lane>>4, dl=lane&15)
    const int kq = lane >> 4, dl = lane & 15;
    const float p0a = __shfl(p0, kq * 8);
    const float p0b = __shfl(p0, (kq + 4) * 8);
    float ag = p0a * rowbuf[w][rowoff(64 + kq) + dl]
             + p0b * rowbuf[w][rowoff(64 + kq + 4) + dl];
    ag += __shfl_xor(ag, 16);
    ag += __shfl_xor(ag, 32);           // every lane: ag0 for d = dl
    WAVE_LDS_FENCE();   // Ms ready

    // ---- h1[k][dl] = sigmoid(M[k] @ W + b); lane covers ko=kq and kq+4
    float h1a, h1b;
    {
        float a1 = bval, a2 = bval;
#pragma unroll
        for (int din = 0; din < D; ++din) {
            float wcol = Ws[w][din][dl];
            a1 += Ms[w][kq][din]     * wcol;
            a2 += Ms[w][kq + 4][din] * wcol;
        }
        h1a = 1.0f / (1.0f + expf(-a1));
        h1b = 1.0f / (1.0f + expf(-a2));
    }

    // ---- h0[dl] = sigmoid((q0 + ag0) @ W + b)  (q0 broadcast from rowbuf)
    float a0acc = bval;
#pragma unroll
    for (int din = 0; din < D; ++din) {
        float q0d = rowbuf[w][rowoff(72) + din];
        float agd = __shfl(ag, din);    // lane 'din' holds ag0[din]
        a0acc += (q0d + agd) * Ws[w][din][dl];
    }
    const float h0v = 1.0f / (1.0f + expf(-a0acc));

    // ---- M1[dl] = h0[dl] + sum_k p0_k h1[k][dl]  (h1 values already local!)
    float v1 = p0a * h1a + p0b * h1b;
    v1 += __shfl_xor(v1, 16);
    v1 += __shfl_xor(v1, 32);
    const float M1 = h0v + v1;          // every lane: M1 for d = dl

    // ---- final: item[dl] = relu(tanh(M1 @ W + b))
    float fin = bval;
#pragma unroll
    for (int din = 0; din < D; ++din)
        fin += __shfl(M1, din) * Ws[w][din][dl];
    if (lane < D) item[(long)p * D + lane] = fmaxf(tanhf(fin), 0.0f);
}

// ---------------------------------------------------------------------------
// Fused tail (one block per b, 128 threads): diffusion MLP (all threads) +
// fusion head (t<64). Independent outputs; barriers reached by all threads.
// ---------------------------------------------------------------------------
__global__ __launch_bounds__(128) void k_tail(
    const float* __restrict__ item,     // [B*S, D]
    const float* __restrict__ fc1_W, const float* __restrict__ fc1_b,
    const float* __restrict__ fc2_W, const float* __restrict__ fc2_b,
    const float* __restrict__ ent_emb, const int* __restrict__ v,
    const float* __restrict__ usr_emb, const float* __restrict__ noise_e,
    const int* __restrict__ u, const int* __restrict__ t_arr,
    const float* __restrict__ W1, const float* __restrict__ b1,
    const float* __restrict__ W2, const float* __restrict__ b2,
    const float* __restrict__ W3, const float* __restrict__ b3,
    const float* __restrict__ W4, const float* __restrict__ b4,
    const float* __restrict__ se1, const float* __restrict__ se2,
    const float* __restrict__ se3,
    const float* __restrict__ sa, const float* __restrict__ so,
    float* __restrict__ out)            // [B, 17]
{
    __shared__ float x0[D];
    __shared__ float ha[NUNITS];
    __shared__ float hb[NUNITS];
    __shared__ float sm[S][D + 1];
    __shared__ float fus[2 * D];
    __shared__ float hid[64];
    __shared__ float feat_s[D];

    int b = blockIdx.x, t = threadIdx.x;
    int ts = t_arr[b];

    // ======== diffusion MLP ========
    if (t < D)
        x0[t] = usr_emb[(long)u[b] * D + t] * sa[ts] + noise_e[(long)b * D + t] * so[ts];
    __syncthreads();

    float a = b1[t] + se1[(long)ts * NUNITS + t];
#pragma unroll
    for (int i = 0; i < D; ++i) a += x0[i] * W1[i * NUNITS + t];
    ha[t] = fmaxf(a, 0.0f);
    __syncthreads();

    a = b2[t] + se2[(long)ts * NUNITS + t];
    for (int i = 0; i < NUNITS; ++i) a += ha[i] * W2[i * NUNITS + t];
    hb[t] = fmaxf(a, 0.0f);
    __syncthreads();

    a = b3[t] + se3[(long)ts * NUNITS + t];
    for (int i = 0; i < NUNITS; ++i) a += hb[i] * W3[i * NUNITS + t];
    __syncthreads();
    ha[t] = fmaxf(a, 0.0f);
    __syncthreads();

    if (t < D) {
        float acc = b4[t];
        for (int i = 0; i < NUNITS; ++i) acc += ha[i] * W4[i * D + t];
        out[(long)b * 17 + 1 + t] = acc;
    }

    // ======== fusion head (threads < 64 active; barriers hit by all) ========
    if (t < 64) {
        const float4* ip = (const float4*)(item + ((long)b * S + t) * D);
        float4 r0 = ip[0], r1 = ip[1], r2 = ip[2], r3 = ip[3];
        sm[t][0]=r0.x;  sm[t][1]=r0.y;  sm[t][2]=r0.z;  sm[t][3]=r0.w;
        sm[t][4]=r1.x;  sm[t][5]=r1.y;  sm[t][6]=r1.z;  sm[t][7]=r1.w;
        sm[t][8]=r2.x;  sm[t][9]=r2.y;  sm[t][10]=r2.z; sm[t][11]=r2.w;
        sm[t][12]=r3.x; sm[t][13]=r3.y; sm[t][14]=r3.z; sm[t][15]=r3.w;
    }
    __syncthreads();

    if (t < D) {
        float sv = 0.0f, mv = -1e30f;
        for (int ss = 0; ss < S; ++ss) {
            float x = sm[ss][t];
            sv += x;
            mv = fmaxf(mv, x);
        }
        fus[t] = fmaxf(sv, 0.0f);
        fus[D + t] = fmaxf(mv, 0.0f);
    }
    __syncthreads();

    if (t < 64) {
        float acc = fc1_b[t];
#pragma unroll
        for (int i = 0; i < 2 * D; ++i) acc += fus[i] * fc1_W[i * 64 + t];
        hid[t] = fmaxf(acc, 0.0f);
    }
    __syncthreads();

    if (t < D) {
        float f = fc2_b[t];
#pragma unroll
        for (int i = 0; i < 64; ++i) f += hid[i] * fc2_W[i * D + t];
        feat_s[t] = fmaxf(f, 0.0f);
    }
    __syncthreads();

    if (t < D) {
        float g = feat_s[t] * ent_emb[(long)v[b] * D + t];
        g += __shfl_xor(g, 1);
        g += __shfl_xor(g, 2);
        g += __shfl_xor(g, 4);
        g += __shfl_xor(g, 8);
        if (t == 0) out[(long)b * 17] = 1.0f / (1.0f + expf(-g));
    }
}

// ---------------------------------------------------------------------------
extern "C" void kernel_launch(void* const* d_in, const int* in_sizes, int n_in,
                              void* d_out, int out_size, void* d_ws, size_t ws_size,
                              hipStream_t stream) {
    const float* usr_emb = (const float*)d_in[0];
    const float* ent_emb = (const float*)d_in[1];
    const float* rel_emb = (const float*)d_in[2];
    const float* agg_W   = (const float*)d_in[3];
    const float* agg_b   = (const float*)d_in[4];
    const float* fc1_W   = (const float*)d_in[5];
    const float* fc1_b   = (const float*)d_in[6];
    const float* fc2_W   = (const float*)d_in[7];
    const float* fc2_b   = (const float*)d_in[8];
    const float* mlp_W1  = (const float*)d_in[9];
    const float* mlp_b1  = (const float*)d_in[10];
    const float* mlp_W2  = (const float*)d_in[11];
    const float* mlp_b2  = (const float*)d_in[12];
    const float* mlp_W3  = (const float*)d_in[13];
    const float* mlp_b3  = (const float*)d_in[14];
    const float* mlp_W4  = (const float*)d_in[15];
    const float* mlp_b4  = (const float*)d_in[16];
    const float* se1     = (const float*)d_in[17];
    const float* se2     = (const float*)d_in[18];
    const float* se3     = (const float*)d_in[19];
    const float* noise_e = (const float*)d_in[20];
    const int* u         = (const int*)d_in[21];
    const int* v         = (const int*)d_in[22];
    const int* click_seq = (const int*)d_in[23];
    const int* adj_ent   = (const int*)d_in[24];
    const int* adj_rel   = (const int*)d_in[25];
    const int* t         = (const int*)d_in[26];
    float* out = (float*)d_out;

    float* ws = (float*)d_ws;
    float* w_tab = ws;                         // B*NR floats
    float* sa    = w_tab + B * NR;             // 128 floats (NSTEPS used)
    float* so    = sa + 128;                   // 128 floats
    float* item  = so + 128;                   // B*S*D floats
    int*   e1s   = (int*)(item + B * S * D);   // B*S*K ints
    int*   r0s   = e1s + B * S * K;            // B*S*K ints

    k_prep_all<<<B, 256, 0, stream>>>(usr_emb, rel_emb, u, click_seq, adj_ent, adj_rel,
                                      w_tab, e1s, r0s, sa, so);
    k_kgcn<<<(B * S) / 4, 256, 0, stream>>>(ent_emb, w_tab, click_seq, adj_ent, adj_rel,
                                            e1s, r0s, agg_W, agg_b, item);
    k_tail<<<B, 128, 0, stream>>>(item, fc1_W, fc1_b, fc2_W, fc2_b, ent_emb, v,
                                  usr_emb, noise_e, u, t, mlp_W1, mlp_b1, mlp_W2, mlp_b2,
                                  mlp_W3, mlp_b3, mlp_W4, mlp_b4, se1, se2, se3, sa, so, out);
}